// Round 1
// baseline (28.200 us; speedup 1.0000x reference)
//
#include <hip/hip_runtime.h>
#include <math.h>

#define HDIM 128

// Wave-parallel lower_bound: smallest idx with seg[idx] >= target, in [0, N].
// Must be called by all 64 lanes of a wave with uniform (N, target).
__device__ __forceinline__ int wave_lower_bound(const int* __restrict__ seg, int N, int target) {
    const int lane = threadIdx.x & 63;
    int lo = 0, hi = N;                       // answer in [lo, hi]
    while (hi - lo > 64) {
        int len = hi - lo;
        int chunk = (len + 63) >> 6;          // >= 2
        int pos = lo + lane * chunk;          // lane 0 probes lo
        int v = (pos < hi) ? seg[pos] : 0x7fffffff;
        unsigned long long bal = __ballot(v < target);
        int cnt = __popcll(bal);              // sorted -> lanes 0..cnt-1 true
        if (cnt == 0) { hi = lo; break; }     // seg[lo] >= target -> answer == lo
        int nlo = lo + (cnt - 1) * chunk + 1; // seg at (cnt-1)*chunk < target
        int nhi = (cnt < 64) ? min(hi, lo + cnt * chunk) : hi;
        lo = nlo; hi = nhi;
    }
    int pos = lo + lane;
    int v = (pos < hi) ? seg[pos] : 0x7fffffff;
    unsigned long long bal = __ballot(v < target);
    return lo + __popcll(bal);
}

__global__ void __launch_bounds__(1024)
att_pool_kernel(const float* __restrict__ s,      // [B,H]
                const float* __restrict__ x,      // [N,H] node_embeds
                const float* __restrict__ W,      // [H,H]
                const int*   __restrict__ seg,    // [N] sorted
                float*       __restrict__ out,    // [B,H]
                int N, int B)
{
    const int b    = blockIdx.x;
    const int tid  = threadIdx.x;
    const int wave = tid >> 6;        // 0..15
    const int lane = tid & 63;
    const int half = lane >> 5;       // 0 or 1 (which node of the pair)
    const int hl   = lane & 31;       // lane within half: owns channels 4*hl..4*hl+3

    __shared__ float ws_lds[HDIM];
    __shared__ int   se[2];
    __shared__ float lm[32], ll[32];
    __shared__ float lacc[32][HDIM];
    __shared__ float sscale[32];
    __shared__ float sdenom;

    // ---- Phase 1: ws_b = W @ s_b  (ws[k] = sum_j W[k,j] * s[b,j]) ----
    {
        const int kloc = lane >> 3;           // 0..7
        const int g    = lane & 7;            // 0..7
        const int k    = wave * 8 + kloc;     // 0..127
        const float* Wr = W + (size_t)k * HDIM;
        const float* sr = s + (size_t)b * HDIM;
        float partial = 0.f;
        #pragma unroll
        for (int ii = 0; ii < 4; ++ii) {
            int j0 = (g + 8 * ii) * 4;        // lanes cover 32 float4 chunks
            float4 wv4 = *reinterpret_cast<const float4*>(Wr + j0);
            float4 sv4 = *reinterpret_cast<const float4*>(sr + j0);
            partial += wv4.x * sv4.x + wv4.y * sv4.y + wv4.z * sv4.z + wv4.w * sv4.w;
        }
        partial += __shfl_xor(partial, 1, 64);
        partial += __shfl_xor(partial, 2, 64);
        partial += __shfl_xor(partial, 4, 64);
        if (g == 0) ws_lds[k] = partial;
    }

    // ---- Phase 2: segment bounds (sorted ids -> contiguous range) ----
    if (wave == 0) {
        int v = wave_lower_bound(seg, N, b);
        if (lane == 0) se[0] = v;
    } else if (wave == 1) {
        int v = wave_lower_bound(seg, N, b + 1);
        if (lane == 0) se[1] = v;
    }
    __syncthreads();

    const int start = se[0];
    const int end   = se[1];
    const float4 wv = *reinterpret_cast<const float4*>(&ws_lds[4 * hl]);

    // ---- Phase 3: one-pass online softmax + weighted accumulation ----
    // Each half-wave owns one node per pair; 16 waves * 2 halves = 32 nodes per
    // sweep; unrolled x2 -> stride 64 nodes per loop iteration.
    float  m = -INFINITY, l = 0.f;
    float4 acc = make_float4(0.f, 0.f, 0.f, 0.f);

    for (int p0 = start + 2 * wave; p0 < end; p0 += 64) {
        const int nA = p0 + half;
        const int nB = p0 + 32 + half;
        const bool vA = nA < end;
        const bool vB = nB < end;
        float4 xA = make_float4(0.f, 0.f, 0.f, 0.f);
        float4 xB = make_float4(0.f, 0.f, 0.f, 0.f);
        if (vA) xA = *reinterpret_cast<const float4*>(x + (size_t)nA * HDIM + 4 * hl);
        if (vB) xB = *reinterpret_cast<const float4*>(x + (size_t)nB * HDIM + 4 * hl);

        float hA = xA.x * wv.x + xA.y * wv.y + xA.z * wv.z + xA.w * wv.w;
        float hB = xB.x * wv.x + xB.y * wv.y + xB.z * wv.z + xB.w * wv.w;
        #pragma unroll
        for (int off = 16; off >= 1; off >>= 1) {   // reduce within 32-lane half
            hA += __shfl_xor(hA, off, 64);
            hB += __shfl_xor(hB, off, 64);
        }

        if (vA) {
            float mn = fmaxf(m, hA);
            float sc = __expf(m - mn);
            float e  = __expf(hA - mn);
            l = l * sc + e;
            acc.x = acc.x * sc + e * xA.x;
            acc.y = acc.y * sc + e * xA.y;
            acc.z = acc.z * sc + e * xA.z;
            acc.w = acc.w * sc + e * xA.w;
            m = mn;
        }
        if (vB) {
            float mn = fmaxf(m, hB);
            float sc = __expf(m - mn);
            float e  = __expf(hB - mn);
            l = l * sc + e;
            acc.x = acc.x * sc + e * xB.x;
            acc.y = acc.y * sc + e * xB.y;
            acc.z = acc.z * sc + e * xB.z;
            acc.w = acc.w * sc + e * xB.w;
            m = mn;
        }
    }

    // ---- Phase 4: merge the 32 half-wave online-softmax states ----
    const int st = wave * 2 + half;
    *reinterpret_cast<float4*>(&lacc[st][4 * hl]) = acc;
    if (hl == 0) { lm[st] = m; ll[st] = l; }
    __syncthreads();

    if (tid == 0) {
        float M = -INFINITY;
        #pragma unroll
        for (int i = 0; i < 32; ++i) M = fmaxf(M, lm[i]);
        float D = 0.f;
        #pragma unroll
        for (int i = 0; i < 32; ++i) {
            float sc = (ll[i] > 0.f) ? __expf(lm[i] - M) : 0.f;  // guards empty states (m=-inf)
            sscale[i] = sc;
            D += ll[i] * sc;
        }
        sdenom = D;
    }
    __syncthreads();

    if (tid < HDIM) {
        float num = 0.f;
        #pragma unroll
        for (int i = 0; i < 32; ++i) num += lacc[i][tid] * sscale[i];
        float D = sdenom;
        out[(size_t)b * HDIM + tid] = (D > 0.f) ? (num / D) : 0.f;  // empty segment -> 0
    }
}

extern "C" void kernel_launch(void* const* d_in, const int* in_sizes, int n_in,
                              void* d_out, int out_size, void* d_ws, size_t ws_size,
                              hipStream_t stream) {
    const float* s   = (const float*)d_in[0];  // [B,H]
    const float* x   = (const float*)d_in[1];  // [N,H]
    const float* W   = (const float*)d_in[2];  // [H,H]
    const int*   seg = (const int*)  d_in[3];  // [N]
    float* out = (float*)d_out;

    const int B = in_sizes[0] / HDIM;
    const int N = in_sizes[3];

    att_pool_kernel<<<B, 1024, 0, stream>>>(s, x, W, seg, out, N, B);
}